// Round 2
// baseline (1829.904 us; speedup 1.0000x reference)
//
#include <hip/hip_runtime.h>
#include <hip/hip_bf16.h>

#define NRBF 20
#define FEATC 128

__device__ __forceinline__ float bf2f(unsigned short u) {
    return __uint_as_float(((unsigned)u) << 16);
}
__device__ __forceinline__ unsigned short f2bf(float f) {
    unsigned u = __float_as_uint(f);
    u += 0x7FFF + ((u >> 16) & 1);   // round-to-nearest-even
    return (unsigned short)(u >> 16);
}
// dtype-flag-dependent scalar load/store (isbf uniform per kernel)
__device__ __forceinline__ float ldin(const void* p, size_t idx, int isbf) {
    return isbf ? bf2f(((const unsigned short*)p)[idx]) : ((const float*)p)[idx];
}
__device__ __forceinline__ void stout(void* p, size_t idx, float v, int isbf) {
    if (isbf) ((unsigned short*)p)[idx] = f2bf(v);
    else      ((float*)p)[idx] = v;
}

// ---------------- dtype detector ----------------
// If inputs are f32 and we read even-index ushorts as bf16, ~43% decode to
// exponent >= 0x90 (mantissa garbage). Genuine bf16 xyz ~ N(0,2) never does.
__global__ void detect_kernel(const void* __restrict__ xyz, int* __restrict__ flag) {
    if (threadIdx.x == 0 && blockIdx.x == 0) {
        const unsigned short* u = (const unsigned short*)xyz;
        int bad = 0;
        for (int k = 0; k < 256; k++) {
            unsigned e = (u[2 * k] >> 7) & 0xFF;
            if (e >= 0x90) bad++;
        }
        *flag = (bad > 8) ? 0 : 1;  // 1 = bf16, 0 = f32
    }
}

// ---------------- init: s_acc (f32) <- cg_s ----------------
__global__ void init_s_kernel(const void* __restrict__ cg_s,
                              float* __restrict__ s_acc, int n,
                              const int* __restrict__ flagp) {
    int isbf = *flagp;
    int idx = blockIdx.x * blockDim.x + threadIdx.x;
    if (idx < n) s_acc[idx] = ldin(cg_s, idx, isbf);
}

// ---------------- per-edge geometry: unit, env, rbf ----------------
__global__ void geom_kernel(const void* __restrict__ xyz,
                            const int* __restrict__ nbr,
                            float* __restrict__ unitv, float* __restrict__ rbf,
                            float* __restrict__ env, int E,
                            const int* __restrict__ flagp) {
    int isbf = *flagp;
    int e = blockIdx.x * blockDim.x + threadIdx.x;
    if (e >= E) return;
    int i = nbr[2 * e], j = nbr[2 * e + 1];
    float dx = ldin(xyz, 3 * j,     isbf) - ldin(xyz, 3 * i,     isbf);
    float dy = ldin(xyz, 3 * j + 1, isbf) - ldin(xyz, 3 * i + 1, isbf);
    float dz = ldin(xyz, 3 * j + 2, isbf) - ldin(xyz, 3 * i + 2, isbf);
    float d2 = dx * dx + dy * dy + dz * dz + 3e-15f;  // (r^2 + EPS).sum()
    float dist = sqrtf(d2);
    float inv = 1.0f / dist;
    unitv[3 * e] = dx * inv; unitv[3 * e + 1] = dy * inv; unitv[3 * e + 2] = dz * inv;
    constexpr float PI = 3.14159265358979323846f;
    env[e] = (dist < 5.0f) ? 0.5f * (cosf(PI * dist * 0.2f) + 1.0f) : 0.0f;
    constexpr double EM5 = 0.006737946999085467;  // exp(-5)
    constexpr float MU0 = (float)EM5;
    constexpr float DMU = (float)((1.0 - EM5) / 19.0);
    constexpr float BETA = (float)(1.0 / ((0.1 * (1.0 - EM5)) * (0.1 * (1.0 - EM5))));
    float ed = expf(-dist);
    #pragma unroll
    for (int k = 0; k < NRBF; k++) {
        float dmu = ed - (MU0 + k * DMU);
        rbf[e * NRBF + k] = expf(-BETA * dmu * dmu);
    }
}

// ---------------- tiled GEMM: C(MxNc) = act(A(MxK=128) @ B + bias) ----------------
// A: f32 row-major; B,bias: bf16 OR f32 (flag); C: f32. ACT=1 -> silu.
template <int ACT>
__global__ __launch_bounds__(256) void gemm_bias(const float* __restrict__ A,
                                                 const void* __restrict__ B, size_t Boff,
                                                 const void* __restrict__ bias, size_t biasoff,
                                                 float* __restrict__ C, int M, int Ncols,
                                                 const int* __restrict__ flagp) {
    int isbf = *flagp;
    __shared__ float As[64][17];
    __shared__ __align__(16) float Bs[16][64];
    int tid = threadIdx.x;
    int tx = tid & 15, ty = tid >> 4;
    int brow = blockIdx.x * 64;
    int bcol = blockIdx.y * 64;
    float acc[4][4] = {};
    for (int k0 = 0; k0 < FEATC; k0 += 16) {
        {   // A tile: 64 rows x 16 k, float4 per thread
            int r = tid >> 2;
            int kk0 = (tid & 3) * 4;
            int row = brow + r;
            float4 av = make_float4(0.f, 0.f, 0.f, 0.f);
            if (row < M) av = *reinterpret_cast<const float4*>(&A[(size_t)row * FEATC + k0 + kk0]);
            As[r][kk0 + 0] = av.x; As[r][kk0 + 1] = av.y;
            As[r][kk0 + 2] = av.z; As[r][kk0 + 3] = av.w;
        }
        {   // B tile: 16 k x 64 cols, 4 elements per thread
            int kk = tid >> 4;
            int nc0 = (tid & 15) * 4;
            size_t bidx = Boff + (size_t)(k0 + kk) * Ncols + bcol + nc0;
            if (isbf) {
                const unsigned short* Bu = (const unsigned short*)B;
                ushort4 bv = *reinterpret_cast<const ushort4*>(&Bu[bidx]);
                Bs[kk][nc0 + 0] = bf2f(bv.x); Bs[kk][nc0 + 1] = bf2f(bv.y);
                Bs[kk][nc0 + 2] = bf2f(bv.z); Bs[kk][nc0 + 3] = bf2f(bv.w);
            } else {
                const float* Bf = (const float*)B;
                float4 bv = *reinterpret_cast<const float4*>(&Bf[bidx]);
                Bs[kk][nc0 + 0] = bv.x; Bs[kk][nc0 + 1] = bv.y;
                Bs[kk][nc0 + 2] = bv.z; Bs[kk][nc0 + 3] = bv.w;
            }
        }
        __syncthreads();
        #pragma unroll
        for (int kk = 0; kk < 16; kk++) {
            float a0 = As[ty * 4 + 0][kk];
            float a1 = As[ty * 4 + 1][kk];
            float a2 = As[ty * 4 + 2][kk];
            float a3 = As[ty * 4 + 3][kk];
            float4 b = *reinterpret_cast<const float4*>(&Bs[kk][tx * 4]);
            acc[0][0] += a0 * b.x; acc[0][1] += a0 * b.y; acc[0][2] += a0 * b.z; acc[0][3] += a0 * b.w;
            acc[1][0] += a1 * b.x; acc[1][1] += a1 * b.y; acc[1][2] += a1 * b.z; acc[1][3] += a1 * b.w;
            acc[2][0] += a2 * b.x; acc[2][1] += a2 * b.y; acc[2][2] += a2 * b.z; acc[2][3] += a2 * b.w;
            acc[3][0] += a3 * b.x; acc[3][1] += a3 * b.y; acc[3][2] += a3 * b.z; acc[3][3] += a3 * b.w;
        }
        __syncthreads();
    }
    #pragma unroll
    for (int i2 = 0; i2 < 4; i2++) {
        int row = brow + ty * 4 + i2;
        if (row >= M) continue;
        #pragma unroll
        for (int jj = 0; jj < 4; jj++) {
            int col = bcol + tx * 4 + jj;
            float x = acc[i2][jj] + ldin(bias, biasoff + col, isbf);
            if (ACT) x = x / (1.0f + expf(-x));  // silu
            C[(size_t)row * Ncols + col] = x;
        }
    }
}

// ---------------- edge kernel: w_s, prod, scatter-add ----------------
// 128 threads cooperate per edge; thread t owns output features {t, t+128, t+256}.
#define EPB 8
__global__ __launch_bounds__(128) void edge_kernel(const int* __restrict__ nbr,
                                                   const float* __restrict__ env,
                                                   const float* __restrict__ unitv,
                                                   const float* __restrict__ rbf,
                                                   const float* __restrict__ phi,
                                                   const void* __restrict__ Wr, size_t wroff,
                                                   const void* __restrict__ br, size_t broff,
                                                   const float* __restrict__ v_old,
                                                   float* __restrict__ s_acc,
                                                   float* __restrict__ v_new, int E,
                                                   const int* __restrict__ flagp) {
    int isbf = *flagp;
    __shared__ float WrS[NRBF * 384];   // 30 KB
    __shared__ float brS[384];
    int t = threadIdx.x;
    for (int idx = t; idx < NRBF * 384; idx += 128) WrS[idx] = ldin(Wr, wroff + idx, isbf);
    for (int idx = t; idx < 384; idx += 128) brS[idx] = ldin(br, broff + idx, isbf);
    __syncthreads();
    int e0 = blockIdx.x * EPB;
    for (int k = 0; k < EPB; k++) {
        int e = e0 + k;
        if (e >= E) break;
        float ev = env[e];
        if (ev == 0.0f) continue;  // ~half the edges contribute exactly 0
        int i = nbr[2 * e], j = nbr[2 * e + 1];
        float rb[NRBF];
        #pragma unroll
        for (int r = 0; r < NRBF; r++) rb[r] = rbf[e * NRBF + r];
        float ux = unitv[3 * e], uy = unitv[3 * e + 1], uz = unitv[3 * e + 2];
        float w0 = brS[t], w1 = brS[t + 128], w2 = brS[t + 256];
        #pragma unroll
        for (int r = 0; r < NRBF; r++) {
            float rv = rb[r];
            w0 += rv * WrS[r * 384 + t];
            w1 += rv * WrS[r * 384 + t + 128];
            w2 += rv * WrS[r * 384 + t + 256];
        }
        w0 *= ev; w1 *= ev; w2 *= ev;
        size_t jb = (size_t)j * 384;
        float ds = phi[jb + t] * w0;             // prod[:, :128]
        float gv = phi[jb + 128 + t] * w1;       // gate_v
        float gu = phi[jb + 256 + t] * w2;       // gate_u
        atomicAdd(&s_acc[(size_t)i * 128 + t], ds);
        float vx = v_old[jb + t * 3];
        float vy = v_old[jb + t * 3 + 1];
        float vz = v_old[jb + t * 3 + 2];
        size_t ib = (size_t)i * 384 + t * 3;
        atomicAdd(&v_new[ib],     gu * ux + gv * vx);
        atomicAdd(&v_new[ib + 1], gu * uy + gv * vy);
        atomicAdd(&v_new[ib + 2], gu * uz + gv * vz);
    }
}

// ---------------- final cast to output dtype ----------------
__global__ void cast_out_kernel(const float* __restrict__ s_acc,
                                const float* __restrict__ v_fin,
                                void* __restrict__ out, int N,
                                const int* __restrict__ flagp) {
    int isbf = *flagp;
    int idx = blockIdx.x * blockDim.x + threadIdx.x;
    int ns = N * 128;
    int tot = N * 512;
    if (idx < ns) stout(out, idx, s_acc[idx], isbf);
    else if (idx < tot) stout(out, idx, v_fin[idx - ns], isbf);
}

extern "C" void kernel_launch(void* const* d_in, const int* in_sizes, int n_in,
                              void* d_out, int out_size, void* d_ws, size_t ws_size,
                              hipStream_t stream) {
    const int N = in_sizes[0] / 3;
    const int E = in_sizes[1] / 2;
    const void* xyz  = d_in[0];
    const int*  nbr  = (const int*)d_in[1];
    const void* cg_s = d_in[2];
    const void* W1   = d_in[3];
    const void* b1   = d_in[4];
    const void* W2   = d_in[5];
    const void* b2   = d_in[6];
    const void* Wr   = d_in[7];
    const void* br   = d_in[8];

    int*   flag  = (int*)d_ws;
    float* s_acc = (float*)((char*)d_ws + 64);
    float* h     = s_acc + (size_t)N * 128;
    float* phi   = h     + (size_t)N * 128;
    float* vA    = phi   + (size_t)N * 384;
    float* vB    = vA    + (size_t)N * 384;
    float* unitv = vB    + (size_t)N * 384;
    float* rbf   = unitv + (size_t)E * 3;
    float* env   = rbf   + (size_t)E * NRBF;

    detect_kernel<<<1, 64, 0, stream>>>(xyz, flag);
    init_s_kernel<<<(N * 128 + 255) / 256, 256, 0, stream>>>(cg_s, s_acc, N * 128, flag);
    hipMemsetAsync(vA, 0, (size_t)N * 384 * sizeof(float), stream);
    hipMemsetAsync(vB, 0, (size_t)N * 384 * sizeof(float), stream);
    geom_kernel<<<(E + 255) / 256, 256, 0, stream>>>(xyz, nbr, unitv, rbf, env, E, flag);

    for (int l = 0; l < 3; l++) {
        gemm_bias<1><<<dim3((N + 63) / 64, 2), 256, 0, stream>>>(
            s_acc, W1, (size_t)l * 128 * 128, b1, (size_t)l * 128, h, N, 128, flag);
        gemm_bias<0><<<dim3((N + 63) / 64, 6), 256, 0, stream>>>(
            h, W2, (size_t)l * 128 * 384, b2, (size_t)l * 384, phi, N, 384, flag);
        const float* v_old; float* v_new;
        if (l == 0) { v_old = vA; v_new = vB; }
        else if (l == 1) {
            v_old = vB; v_new = vA;
            hipMemcpyAsync(vA, vB, (size_t)N * 384 * sizeof(float), hipMemcpyDeviceToDevice, stream);
        } else {
            v_old = vA; v_new = vB;
            hipMemcpyAsync(vB, vA, (size_t)N * 384 * sizeof(float), hipMemcpyDeviceToDevice, stream);
        }
        edge_kernel<<<(E + EPB - 1) / EPB, 128, 0, stream>>>(
            nbr, env, unitv, rbf, phi, Wr, (size_t)l * NRBF * 384, br, (size_t)l * 384,
            v_old, s_acc, v_new, E, flag);
    }
    cast_out_kernel<<<(N * 512 + 255) / 256, 256, 0, stream>>>(s_acc, vB, d_out, N, flag);
}

// Round 3
// 487.145 us; speedup vs baseline: 3.7564x; 3.7564x over previous
//
#include <hip/hip_runtime.h>
#include <hip/hip_bf16.h>

#define NRBF 20
#define FEATC 128

__device__ __forceinline__ float bf2f(unsigned short u) {
    return __uint_as_float(((unsigned)u) << 16);
}
__device__ __forceinline__ unsigned short f2bf(float f) {
    unsigned u = __float_as_uint(f);
    u += 0x7FFF + ((u >> 16) & 1);   // round-to-nearest-even
    return (unsigned short)(u >> 16);
}
__device__ __forceinline__ float ldin(const void* p, size_t idx, int isbf) {
    return isbf ? bf2f(((const unsigned short*)p)[idx]) : ((const float*)p)[idx];
}
__device__ __forceinline__ void stout(void* p, size_t idx, float v, int isbf) {
    if (isbf) ((unsigned short*)p)[idx] = f2bf(v);
    else      ((float*)p)[idx] = v;
}

// ---------------- dtype detector ----------------
__global__ void detect_kernel(const void* __restrict__ xyz, int* __restrict__ flag) {
    if (threadIdx.x == 0 && blockIdx.x == 0) {
        const unsigned short* u = (const unsigned short*)xyz;
        int bad = 0;
        for (int k = 0; k < 256; k++) {
            unsigned e = (u[2 * k] >> 7) & 0xFF;
            if (e >= 0x90) bad++;
        }
        *flag = (bad > 8) ? 0 : 1;  // 1 = bf16, 0 = f32
    }
}

// ---------------- init: s_acc (f32) <- cg_s ----------------
__global__ void init_s_kernel(const void* __restrict__ cg_s,
                              float* __restrict__ s_acc, int n,
                              const int* __restrict__ flagp) {
    int isbf = *flagp;
    int idx = blockIdx.x * blockDim.x + threadIdx.x;
    if (idx < n) s_acc[idx] = ldin(cg_s, idx, isbf);
}

// ---------------- per-edge geometry: unit, env, rbf*env ----------------
__global__ void geom_kernel(const void* __restrict__ xyz,
                            const int* __restrict__ nbr,
                            float* __restrict__ unitv, float* __restrict__ rbfp,
                            float* __restrict__ env, int E,
                            const int* __restrict__ flagp) {
    int isbf = *flagp;
    int e = blockIdx.x * blockDim.x + threadIdx.x;
    if (e >= E) return;
    int i = nbr[2 * e], j = nbr[2 * e + 1];
    float dx = ldin(xyz, 3 * j,     isbf) - ldin(xyz, 3 * i,     isbf);
    float dy = ldin(xyz, 3 * j + 1, isbf) - ldin(xyz, 3 * i + 1, isbf);
    float dz = ldin(xyz, 3 * j + 2, isbf) - ldin(xyz, 3 * i + 2, isbf);
    float d2 = dx * dx + dy * dy + dz * dz + 3e-15f;
    float dist = sqrtf(d2);
    float inv = 1.0f / dist;
    unitv[3 * e] = dx * inv; unitv[3 * e + 1] = dy * inv; unitv[3 * e + 2] = dz * inv;
    constexpr float PI = 3.14159265358979323846f;
    float ev = (dist < 5.0f) ? 0.5f * (cosf(PI * dist * 0.2f) + 1.0f) : 0.0f;
    env[e] = ev;
    constexpr double EM5 = 0.006737946999085467;  // exp(-5)
    constexpr float MU0 = (float)EM5;
    constexpr float DMU = (float)((1.0 - EM5) / 19.0);
    constexpr float BETA = (float)(1.0 / ((0.1 * (1.0 - EM5)) * (0.1 * (1.0 - EM5))));
    float ed = expf(-dist);
    #pragma unroll
    for (int k = 0; k < NRBF; k++) {
        float dmu = ed - (MU0 + k * DMU);
        rbfp[(size_t)e * NRBF + k] = ev * expf(-BETA * dmu * dmu);  // env folded in
    }
}

// ---------------- CSR build: degree, scan, scatter ----------------
__global__ void deg_kernel(const int* __restrict__ nbr, const float* __restrict__ env,
                           int* __restrict__ deg, int E) {
    int e = blockIdx.x * blockDim.x + threadIdx.x;
    if (e >= E) return;
    if (env[e] != 0.0f) atomicAdd(&deg[nbr[2 * e]], 1);
}

__global__ void scan_kernel(int* __restrict__ deg, int* __restrict__ rowptr, int N) {
    __shared__ int part[256];
    int t = threadIdx.x;
    int chunk = (N + 255) / 256;
    int lo = t * chunk, hi = min(lo + chunk, N);
    int s = 0;
    for (int i = lo; i < hi; i++) s += deg[i];
    part[t] = s;
    __syncthreads();
    for (int off = 1; off < 256; off <<= 1) {
        int v = (t >= off) ? part[t - off] : 0;
        __syncthreads();
        if (t >= off) part[t] += v;
        __syncthreads();
    }
    int base = (t == 0) ? 0 : part[t - 1];
    for (int i = lo; i < hi; i++) {
        rowptr[i] = base;
        int d = deg[i];
        deg[i] = base;   // deg becomes the scatter cursor
        base += d;
    }
    if (t == 0) rowptr[N] = part[255];
}

__global__ void scatter_kernel(const int* __restrict__ nbr, const float* __restrict__ env,
                               int* __restrict__ cursor, int* __restrict__ elist, int E) {
    int e = blockIdx.x * blockDim.x + threadIdx.x;
    if (e >= E) return;
    if (env[e] != 0.0f) {
        int pos = atomicAdd(&cursor[nbr[2 * e]], 1);
        elist[pos] = e;
    }
}

// ---------------- tiled GEMM: C(MxNc) = act(A(MxK=128) @ B + bias) ----------------
template <int ACT>
__global__ __launch_bounds__(256) void gemm_bias(const float* __restrict__ A,
                                                 const void* __restrict__ B, size_t Boff,
                                                 const void* __restrict__ bias, size_t biasoff,
                                                 float* __restrict__ C, int M, int Ncols,
                                                 const int* __restrict__ flagp) {
    int isbf = *flagp;
    __shared__ float As[64][17];
    __shared__ __align__(16) float Bs[16][64];
    int tid = threadIdx.x;
    int tx = tid & 15, ty = tid >> 4;
    int brow = blockIdx.x * 64;
    int bcol = blockIdx.y * 64;
    float acc[4][4] = {};
    for (int k0 = 0; k0 < FEATC; k0 += 16) {
        {
            int r = tid >> 2;
            int kk0 = (tid & 3) * 4;
            int row = brow + r;
            float4 av = make_float4(0.f, 0.f, 0.f, 0.f);
            if (row < M) av = *reinterpret_cast<const float4*>(&A[(size_t)row * FEATC + k0 + kk0]);
            As[r][kk0 + 0] = av.x; As[r][kk0 + 1] = av.y;
            As[r][kk0 + 2] = av.z; As[r][kk0 + 3] = av.w;
        }
        {
            int kk = tid >> 4;
            int nc0 = (tid & 15) * 4;
            size_t bidx = Boff + (size_t)(k0 + kk) * Ncols + bcol + nc0;
            if (isbf) {
                const unsigned short* Bu = (const unsigned short*)B;
                ushort4 bv = *reinterpret_cast<const ushort4*>(&Bu[bidx]);
                Bs[kk][nc0 + 0] = bf2f(bv.x); Bs[kk][nc0 + 1] = bf2f(bv.y);
                Bs[kk][nc0 + 2] = bf2f(bv.z); Bs[kk][nc0 + 3] = bf2f(bv.w);
            } else {
                const float* Bf = (const float*)B;
                float4 bv = *reinterpret_cast<const float4*>(&Bf[bidx]);
                Bs[kk][nc0 + 0] = bv.x; Bs[kk][nc0 + 1] = bv.y;
                Bs[kk][nc0 + 2] = bv.z; Bs[kk][nc0 + 3] = bv.w;
            }
        }
        __syncthreads();
        #pragma unroll
        for (int kk = 0; kk < 16; kk++) {
            float a0 = As[ty * 4 + 0][kk];
            float a1 = As[ty * 4 + 1][kk];
            float a2 = As[ty * 4 + 2][kk];
            float a3 = As[ty * 4 + 3][kk];
            float4 b = *reinterpret_cast<const float4*>(&Bs[kk][tx * 4]);
            acc[0][0] += a0 * b.x; acc[0][1] += a0 * b.y; acc[0][2] += a0 * b.z; acc[0][3] += a0 * b.w;
            acc[1][0] += a1 * b.x; acc[1][1] += a1 * b.y; acc[1][2] += a1 * b.z; acc[1][3] += a1 * b.w;
            acc[2][0] += a2 * b.x; acc[2][1] += a2 * b.y; acc[2][2] += a2 * b.z; acc[2][3] += a2 * b.w;
            acc[3][0] += a3 * b.x; acc[3][1] += a3 * b.y; acc[3][2] += a3 * b.z; acc[3][3] += a3 * b.w;
        }
        __syncthreads();
    }
    #pragma unroll
    for (int i2 = 0; i2 < 4; i2++) {
        int row = brow + ty * 4 + i2;
        if (row >= M) continue;
        #pragma unroll
        for (int jj = 0; jj < 4; jj++) {
            int col = bcol + tx * 4 + jj;
            float x = acc[i2][jj] + ldin(bias, biasoff + col, isbf);
            if (ACT) x = x / (1.0f + expf(-x));  // silu
            C[(size_t)row * Ncols + col] = x;
        }
    }
}

// ---------------- node gather kernel: one block per destination node ----------------
// Thread t owns output features {t, t+128, t+256}; Wr columns live in registers.
// No atomics, no LDS: every node writes its own s/v exactly once.
__global__ __launch_bounds__(128, 4) void node_kernel(
    const int* __restrict__ rowptr, const int* __restrict__ elist,
    const int* __restrict__ nbr, const float* __restrict__ env,
    const float* __restrict__ unitv, const float* __restrict__ rbfp,
    const float* __restrict__ phi,
    const void* __restrict__ Wr, size_t wroff,
    const void* __restrict__ br, size_t broff,
    const float* __restrict__ v_old, float* __restrict__ s_acc,
    float* __restrict__ v_new, int N, const int* __restrict__ flagp) {
    int isbf = *flagp;
    int node = blockIdx.x;
    if (node >= N) return;
    int tt = threadIdx.x;  // 0..127

    // hoist this thread's 3 Wr columns (20 each) + bias into registers
    float wc0[NRBF], wc1[NRBF], wc2[NRBF];
    #pragma unroll
    for (int r = 0; r < NRBF; r++) {
        size_t base = wroff + (size_t)r * 384 + tt;
        wc0[r] = ldin(Wr, base,       isbf);
        wc1[r] = ldin(Wr, base + 128, isbf);
        wc2[r] = ldin(Wr, base + 256, isbf);
    }
    float bb0 = ldin(br, broff + tt,       isbf);
    float bb1 = ldin(br, broff + tt + 128, isbf);
    float bb2 = ldin(br, broff + tt + 256, isbf);

    int start = __builtin_amdgcn_readfirstlane(rowptr[node]);
    int end   = __builtin_amdgcn_readfirstlane(rowptr[node + 1]);

    float dsv = 0.f, ax = 0.f, ay = 0.f, az = 0.f;
    for (int k = start; k < end; k++) {
        int e = __builtin_amdgcn_readfirstlane(elist[k]);
        int j = __builtin_amdgcn_readfirstlane(nbr[2 * e + 1]);
        float ev = env[e];
        float ux = unitv[3 * e], uy = unitv[3 * e + 1], uz = unitv[3 * e + 2];
        float w0 = ev * bb0, w1 = ev * bb1, w2 = ev * bb2;
        #pragma unroll
        for (int r = 0; r < NRBF; r++) {
            float rv = rbfp[(size_t)e * NRBF + r];  // env already folded in
            w0 += rv * wc0[r];
            w1 += rv * wc1[r];
            w2 += rv * wc2[r];
        }
        size_t jb = (size_t)j * 384;
        dsv += phi[jb + tt] * w0;
        float gv = phi[jb + 128 + tt] * w1;
        float gu = phi[jb + 256 + tt] * w2;
        const float* vj = &v_old[jb + (size_t)tt * 3];
        ax += gu * ux + gv * vj[0];
        ay += gu * uy + gv * vj[1];
        az += gu * uz + gv * vj[2];
    }
    s_acc[(size_t)node * 128 + tt] += dsv;
    size_t ib = (size_t)node * 384 + (size_t)tt * 3;
    v_new[ib]     = v_old[ib]     + ax;
    v_new[ib + 1] = v_old[ib + 1] + ay;
    v_new[ib + 2] = v_old[ib + 2] + az;
}

// ---------------- final cast to output dtype ----------------
__global__ void cast_out_kernel(const float* __restrict__ s_acc,
                                const float* __restrict__ v_fin,
                                void* __restrict__ out, int N,
                                const int* __restrict__ flagp) {
    int isbf = *flagp;
    int idx = blockIdx.x * blockDim.x + threadIdx.x;
    int ns = N * 128;
    int tot = N * 512;
    if (idx < ns) stout(out, idx, s_acc[idx], isbf);
    else if (idx < tot) stout(out, idx, v_fin[idx - ns], isbf);
}

extern "C" void kernel_launch(void* const* d_in, const int* in_sizes, int n_in,
                              void* d_out, int out_size, void* d_ws, size_t ws_size,
                              hipStream_t stream) {
    const int N = in_sizes[0] / 3;
    const int E = in_sizes[1] / 2;
    const void* xyz  = d_in[0];
    const int*  nbr  = (const int*)d_in[1];
    const void* cg_s = d_in[2];
    const void* W1   = d_in[3];
    const void* b1   = d_in[4];
    const void* W2   = d_in[5];
    const void* b2   = d_in[6];
    const void* Wr   = d_in[7];
    const void* br   = d_in[8];

    int*   flag   = (int*)d_ws;
    float* s_acc  = (float*)((char*)d_ws + 64);
    float* h      = s_acc  + (size_t)N * 128;
    float* phi    = h      + (size_t)N * 128;
    float* vA     = phi    + (size_t)N * 384;
    float* vB     = vA     + (size_t)N * 384;
    float* unitv  = vB     + (size_t)N * 384;
    float* rbfp   = unitv  + (size_t)E * 3;
    float* env    = rbfp   + (size_t)E * NRBF;
    int*   rowptr = (int*)(env + E);
    int*   deg    = rowptr + (N + 1);     // becomes cursor after scan
    int*   elist  = deg + N;

    detect_kernel<<<1, 64, 0, stream>>>(xyz, flag);
    init_s_kernel<<<(N * 128 + 255) / 256, 256, 0, stream>>>(cg_s, s_acc, N * 128, flag);
    hipMemsetAsync(vA, 0, (size_t)N * 384 * sizeof(float), stream);
    hipMemsetAsync(deg, 0, (size_t)N * sizeof(int), stream);
    geom_kernel<<<(E + 255) / 256, 256, 0, stream>>>(xyz, nbr, unitv, rbfp, env, E, flag);
    deg_kernel<<<(E + 255) / 256, 256, 0, stream>>>(nbr, env, deg, E);
    scan_kernel<<<1, 256, 0, stream>>>(deg, rowptr, N);
    scatter_kernel<<<(E + 255) / 256, 256, 0, stream>>>(nbr, env, deg, elist, E);

    const float* vbufs[4] = {vA, vB, vA, vB};  // l: old=vbufs[l], new=vbufs[l+1]
    for (int l = 0; l < 3; l++) {
        gemm_bias<1><<<dim3((N + 63) / 64, 2), 256, 0, stream>>>(
            s_acc, W1, (size_t)l * 128 * 128, b1, (size_t)l * 128, h, N, 128, flag);
        gemm_bias<0><<<dim3((N + 63) / 64, 6), 256, 0, stream>>>(
            h, W2, (size_t)l * 128 * 384, b2, (size_t)l * 384, phi, N, 384, flag);
        node_kernel<<<N, 128, 0, stream>>>(
            rowptr, elist, nbr, env, unitv, rbfp, phi,
            Wr, (size_t)l * NRBF * 384, br, (size_t)l * 384,
            vbufs[l], s_acc, (float*)vbufs[l + 1], N, flag);
    }
    cast_out_kernel<<<(N * 512 + 255) / 256, 256, 0, stream>>>(s_acc, vB, d_out, N, flag);
}

// Round 4
// 454.694 us; speedup vs baseline: 4.0245x; 1.0714x over previous
//
#include <hip/hip_runtime.h>
#include <hip/hip_bf16.h>

#define NRBF 20
#define FEATC 128

typedef __attribute__((ext_vector_type(8))) short short8;
typedef __attribute__((ext_vector_type(4))) float float4v;

__device__ __forceinline__ float bf2f(unsigned short u) {
    return __uint_as_float(((unsigned)u) << 16);
}
__device__ __forceinline__ unsigned short f2bf(float f) {
    unsigned u = __float_as_uint(f);
    u += 0x7FFF + ((u >> 16) & 1);   // round-to-nearest-even
    return (unsigned short)(u >> 16);
}
__device__ __forceinline__ float ldin(const void* p, size_t idx, int isbf) {
    return isbf ? bf2f(((const unsigned short*)p)[idx]) : ((const float*)p)[idx];
}
__device__ __forceinline__ void stout(void* p, size_t idx, float v, int isbf) {
    if (isbf) ((unsigned short*)p)[idx] = f2bf(v);
    else      ((float*)p)[idx] = v;
}

// ---------------- dtype detector ----------------
__global__ void detect_kernel(const void* __restrict__ xyz, int* __restrict__ flag) {
    if (threadIdx.x == 0 && blockIdx.x == 0) {
        const unsigned short* u = (const unsigned short*)xyz;
        int bad = 0;
        for (int k = 0; k < 256; k++) {
            unsigned e = (u[2 * k] >> 7) & 0xFF;
            if (e >= 0x90) bad++;
        }
        *flag = (bad > 8) ? 0 : 1;  // 1 = bf16, 0 = f32
    }
}

// ---------------- init: s_acc/s_hi/s_lo <- cg_s ----------------
__global__ void init_s_kernel(const void* __restrict__ cg_s,
                              float* __restrict__ s_acc,
                              unsigned short* __restrict__ s_hi,
                              unsigned short* __restrict__ s_lo, int n,
                              const int* __restrict__ flagp) {
    int isbf = *flagp;
    int idx = blockIdx.x * blockDim.x + threadIdx.x;
    if (idx >= n) return;
    float v = ldin(cg_s, idx, isbf);
    s_acc[idx] = v;
    unsigned short hi = f2bf(v);
    s_hi[idx] = hi;
    s_lo[idx] = f2bf(v - bf2f(hi));
}

// ---------------- per-edge geometry ----------------
__global__ void geom_kernel(const void* __restrict__ xyz,
                            const int* __restrict__ nbr,
                            float* __restrict__ unitv, float* __restrict__ rbfp,
                            float* __restrict__ env, int E,
                            const int* __restrict__ flagp) {
    int isbf = *flagp;
    int e = blockIdx.x * blockDim.x + threadIdx.x;
    if (e >= E) return;
    int i = nbr[2 * e], j = nbr[2 * e + 1];
    float dx = ldin(xyz, 3 * j,     isbf) - ldin(xyz, 3 * i,     isbf);
    float dy = ldin(xyz, 3 * j + 1, isbf) - ldin(xyz, 3 * i + 1, isbf);
    float dz = ldin(xyz, 3 * j + 2, isbf) - ldin(xyz, 3 * i + 2, isbf);
    float d2 = dx * dx + dy * dy + dz * dz + 3e-15f;
    float dist = sqrtf(d2);
    float inv = 1.0f / dist;
    unitv[3 * e] = dx * inv; unitv[3 * e + 1] = dy * inv; unitv[3 * e + 2] = dz * inv;
    constexpr float PI = 3.14159265358979323846f;
    float ev = (dist < 5.0f) ? 0.5f * (cosf(PI * dist * 0.2f) + 1.0f) : 0.0f;
    env[e] = ev;
    constexpr double EM5 = 0.006737946999085467;  // exp(-5)
    constexpr float MU0 = (float)EM5;
    constexpr float DMU = (float)((1.0 - EM5) / 19.0);
    constexpr float BETA = (float)(1.0 / ((0.1 * (1.0 - EM5)) * (0.1 * (1.0 - EM5))));
    float ed = expf(-dist);
    #pragma unroll
    for (int k = 0; k < NRBF; k++) {
        float dmu = ed - (MU0 + k * DMU);
        rbfp[(size_t)e * NRBF + k] = ev * expf(-BETA * dmu * dmu);  // env folded in
    }
}

// ---------------- CSR build ----------------
__global__ void deg_kernel(const int* __restrict__ nbr, const float* __restrict__ env,
                           int* __restrict__ deg, int E) {
    int e = blockIdx.x * blockDim.x + threadIdx.x;
    if (e >= E) return;
    if (env[e] != 0.0f) atomicAdd(&deg[nbr[2 * e]], 1);
}

__global__ void scan_kernel(int* __restrict__ deg, int* __restrict__ rowptr, int N) {
    __shared__ int part[256];
    int t = threadIdx.x;
    int chunk = (N + 255) / 256;
    int lo = t * chunk, hi = min(lo + chunk, N);
    int s = 0;
    for (int i = lo; i < hi; i++) s += deg[i];
    part[t] = s;
    __syncthreads();
    for (int off = 1; off < 256; off <<= 1) {
        int v = (t >= off) ? part[t - off] : 0;
        __syncthreads();
        if (t >= off) part[t] += v;
        __syncthreads();
    }
    int base = (t == 0) ? 0 : part[t - 1];
    for (int i = lo; i < hi; i++) {
        rowptr[i] = base;
        int d = deg[i];
        deg[i] = base;   // deg becomes scatter cursor
        base += d;
    }
    if (t == 0) rowptr[N] = part[255];
}

__global__ void scatter_kernel(const int* __restrict__ nbr, const float* __restrict__ env,
                               int* __restrict__ cursor, int* __restrict__ elist, int E) {
    int e = blockIdx.x * blockDim.x + threadIdx.x;
    if (e >= E) return;
    if (env[e] != 0.0f) {
        int pos = atomicAdd(&cursor[nbr[2 * e]], 1);
        elist[pos] = e;
    }
}

// ---------------- weight-fragment prep: split-bf16 into MFMA B-operand order ----------
// B-frag layout per layer: [ks(4)][ntile][lane(64)][j(8)]; element j = B[ks*32+quad*8+j][nt*16+(lane&15)]
__global__ void prep_frags_kernel(const void* __restrict__ W1, const void* __restrict__ W2,
                                  unsigned short* __restrict__ B1hi, unsigned short* __restrict__ B1lo,
                                  unsigned short* __restrict__ B2hi, unsigned short* __restrict__ B2lo,
                                  const int* __restrict__ flagp) {
    int isbf = *flagp;
    int idx = blockIdx.x * blockDim.x + threadIdx.x;
    const int NW1 = 3 * 4 * 8 * 64;    // 6144 frag-threads for W1 (ntiles=8)
    const int NW2 = 3 * 4 * 24 * 64;   // 18432 for W2 (ntiles=24)
    if (idx < NW1) {
        int lane = idx & 63;
        int t = idx >> 6;
        int nt = t % 8; t /= 8;
        int ks = t % 4; int l = t / 4;
        int n = lane & 15, quad = lane >> 4;
        int col = nt * 16 + n;
        size_t base = (size_t)l * 128 * 128;
        size_t fo = (size_t)idx * 8;
        #pragma unroll
        for (int j = 0; j < 8; j++) {
            int k = ks * 32 + quad * 8 + j;
            float v = ldin(W1, base + (size_t)k * 128 + col, isbf);
            unsigned short hi = f2bf(v);
            B1hi[fo + j] = hi;
            B1lo[fo + j] = f2bf(v - bf2f(hi));
        }
    } else if (idx < NW1 + NW2) {
        int i2 = idx - NW1;
        int lane = i2 & 63;
        int t = i2 >> 6;
        int nt = t % 24; t /= 24;
        int ks = t % 4; int l = t / 4;
        int n = lane & 15, quad = lane >> 4;
        int col = nt * 16 + n;
        size_t base = (size_t)l * 128 * 384;
        size_t fo = (size_t)i2 * 8;
        #pragma unroll
        for (int j = 0; j < 8; j++) {
            int k = ks * 32 + quad * 8 + j;
            float v = ldin(W2, base + (size_t)k * 384 + col, isbf);
            unsigned short hi = f2bf(v);
            B2hi[fo + j] = hi;
            B2lo[fo + j] = f2bf(v - bf2f(hi));
        }
    }
}

// ---------------- MFMA GEMM (split-bf16): C = act(A@B + bias) ----------------
// A given as bf16 hi/lo pair [M][128]; B as prepped frags. Block 256 = 4 waves,
// wave handles 16 rows x 64 cols (4 n-subtiles), K=128 in 4 steps of 32.
// OUTMODE 0: write split hi/lo bf16; OUTMODE 1: write single bf16.
template <int ACT, int OUTMODE>
__global__ __launch_bounds__(256) void mfma_gemm(
    const unsigned short* __restrict__ Ahi, const unsigned short* __restrict__ Alo,
    const unsigned short* __restrict__ Bhi, const unsigned short* __restrict__ Blo,
    const void* __restrict__ bias, size_t biasoff,
    unsigned short* __restrict__ out_hi, unsigned short* __restrict__ out_lo,
    int M, int Ncols, const int* __restrict__ flagp) {
    int isbf = *flagp;
    int tid = threadIdx.x;
    int wave = tid >> 6, lane = tid & 63;
    int m = lane & 15, quad = lane >> 4;
    int brow = blockIdx.x * 64 + wave * 16;
    int row = brow + m;
    int ntiles = Ncols >> 4;
    int ntg0 = blockIdx.y * 4;
    float4v acc[4] = {};
    short8 zero8 = {};
    #pragma unroll
    for (int ks = 0; ks < 4; ks++) {
        short8 ah = zero8, al = zero8;
        if (row < M) {
            size_t ao = (size_t)row * 128 + ks * 32 + quad * 8;
            ah = *reinterpret_cast<const short8*>(Ahi + ao);
            al = *reinterpret_cast<const short8*>(Alo + ao);
        }
        #pragma unroll
        for (int nt = 0; nt < 4; nt++) {
            size_t fo = (((size_t)ks * ntiles + ntg0 + nt) * 64 + lane) * 8;
            short8 bh = *reinterpret_cast<const short8*>(Bhi + fo);
            acc[nt] = __builtin_amdgcn_mfma_f32_16x16x32_bf16(ah, bh, acc[nt], 0, 0, 0);
            acc[nt] = __builtin_amdgcn_mfma_f32_16x16x32_bf16(al, bh, acc[nt], 0, 0, 0);
            if (!isbf) {  // f32 inputs: B has a low part too
                short8 bl = *reinterpret_cast<const short8*>(Blo + fo);
                acc[nt] = __builtin_amdgcn_mfma_f32_16x16x32_bf16(ah, bl, acc[nt], 0, 0, 0);
            }
        }
    }
    // epilogue: D layout col=lane&15, row=quad*4+reg
    #pragma unroll
    for (int nt = 0; nt < 4; nt++) {
        int col = blockIdx.y * 64 + nt * 16 + m;
        float bv = ldin(bias, biasoff + col, isbf);
        #pragma unroll
        for (int r = 0; r < 4; r++) {
            int orow = brow + quad * 4 + r;
            if (orow >= M) continue;
            float x = acc[nt][r] + bv;
            if (ACT) x = x / (1.0f + expf(-x));  // silu
            size_t oo = (size_t)orow * Ncols + col;
            unsigned short h = f2bf(x);
            out_hi[oo] = h;
            if (OUTMODE == 0) out_lo[oo] = f2bf(x - bf2f(h));
        }
    }
}

// ---------------- node gather kernel ----------------
// One block per node; thread t owns features {t, t+128, t+256}; Wr cols in regs.
__global__ __launch_bounds__(128, 4) void node_kernel(
    const int* __restrict__ rowptr, const int* __restrict__ elist,
    const int* __restrict__ nbr, const float* __restrict__ env,
    const float* __restrict__ unitv, const float* __restrict__ rbfp,
    const unsigned short* __restrict__ phi,   // bf16 [N][384]
    const void* __restrict__ Wr, size_t wroff,
    const void* __restrict__ br, size_t broff,
    const float* __restrict__ v_old, float* __restrict__ s_acc,
    unsigned short* __restrict__ s_hi, unsigned short* __restrict__ s_lo,
    float* __restrict__ v_new, int N, const int* __restrict__ flagp) {
    int isbf = *flagp;
    int node = blockIdx.x;
    if (node >= N) return;
    int tt = threadIdx.x;  // 0..127

    float wc0[NRBF], wc1[NRBF], wc2[NRBF];
    #pragma unroll
    for (int r = 0; r < NRBF; r++) {
        size_t base = wroff + (size_t)r * 384 + tt;
        wc0[r] = ldin(Wr, base,       isbf);
        wc1[r] = ldin(Wr, base + 128, isbf);
        wc2[r] = ldin(Wr, base + 256, isbf);
    }
    float bb0 = ldin(br, broff + tt,       isbf);
    float bb1 = ldin(br, broff + tt + 128, isbf);
    float bb2 = ldin(br, broff + tt + 256, isbf);

    int start = __builtin_amdgcn_readfirstlane(rowptr[node]);
    int end   = __builtin_amdgcn_readfirstlane(rowptr[node + 1]);

    float dsv = 0.f, ax = 0.f, ay = 0.f, az = 0.f;
    for (int k = start; k < end; k++) {
        int e = __builtin_amdgcn_readfirstlane(elist[k]);
        int j = __builtin_amdgcn_readfirstlane(nbr[2 * e + 1]);
        float ev = env[e];
        float ux = unitv[3 * e], uy = unitv[3 * e + 1], uz = unitv[3 * e + 2];
        float w0 = ev * bb0, w1 = ev * bb1, w2 = ev * bb2;
        #pragma unroll
        for (int r = 0; r < NRBF; r++) {
            float rv = rbfp[(size_t)e * NRBF + r];  // env folded in
            w0 += rv * wc0[r];
            w1 += rv * wc1[r];
            w2 += rv * wc2[r];
        }
        size_t jb = (size_t)j * 384;
        dsv += bf2f(phi[jb + tt]) * w0;
        float gv = bf2f(phi[jb + 128 + tt]) * w1;
        float gu = bf2f(phi[jb + 256 + tt]) * w2;
        const float* vj = &v_old[jb + (size_t)tt * 3];
        ax += gu * ux + gv * vj[0];
        ay += gu * uy + gv * vj[1];
        az += gu * uz + gv * vj[2];
    }
    size_t so = (size_t)node * 128 + tt;
    float snew = s_acc[so] + dsv;
    s_acc[so] = snew;
    unsigned short hi = f2bf(snew);
    s_hi[so] = hi;
    s_lo[so] = f2bf(snew - bf2f(hi));
    size_t ib = (size_t)node * 384 + (size_t)tt * 3;
    v_new[ib]     = v_old[ib]     + ax;
    v_new[ib + 1] = v_old[ib + 1] + ay;
    v_new[ib + 2] = v_old[ib + 2] + az;
}

// ---------------- final cast ----------------
__global__ void cast_out_kernel(const float* __restrict__ s_acc,
                                const float* __restrict__ v_fin,
                                void* __restrict__ out, int N,
                                const int* __restrict__ flagp) {
    int isbf = *flagp;
    int idx = blockIdx.x * blockDim.x + threadIdx.x;
    int ns = N * 128;
    int tot = N * 512;
    if (idx < ns) stout(out, idx, s_acc[idx], isbf);
    else if (idx < tot) stout(out, idx, v_fin[idx - ns], isbf);
}

extern "C" void kernel_launch(void* const* d_in, const int* in_sizes, int n_in,
                              void* d_out, int out_size, void* d_ws, size_t ws_size,
                              hipStream_t stream) {
    const int N = in_sizes[0] / 3;
    const int E = in_sizes[1] / 2;
    const void* xyz  = d_in[0];
    const int*  nbr  = (const int*)d_in[1];
    const void* cg_s = d_in[2];
    const void* W1   = d_in[3];
    const void* b1   = d_in[4];
    const void* W2   = d_in[5];
    const void* b2   = d_in[6];
    const void* Wr   = d_in[7];
    const void* br   = d_in[8];

    int*   flag   = (int*)d_ws;
    float* s_acc  = (float*)((char*)d_ws + 64);
    float* vA     = s_acc  + (size_t)N * 128;
    float* vB     = vA     + (size_t)N * 384;
    float* unitv  = vB     + (size_t)N * 384;
    float* rbfp   = unitv  + (size_t)E * 3;
    float* env    = rbfp   + (size_t)E * NRBF;
    int*   rowptr = (int*)(env + E);
    int*   deg    = rowptr + (N + 16);
    int*   elist  = deg + N;
    unsigned short* s_hi = (unsigned short*)(elist + ((E + 7) & ~7));
    unsigned short* s_lo = s_hi + (size_t)N * 128;
    unsigned short* h_hi = s_lo + (size_t)N * 128;
    unsigned short* h_lo = h_hi + (size_t)N * 128;
    unsigned short* phi  = h_lo + (size_t)N * 128;
    unsigned short* B1hi = phi  + (size_t)N * 384;
    unsigned short* B1lo = B1hi + 3 * 4 * 8 * 64 * 8;
    unsigned short* B2hi = B1lo + 3 * 4 * 8 * 64 * 8;
    unsigned short* B2lo = B2hi + 3 * 4 * 24 * 64 * 8;

    detect_kernel<<<1, 64, 0, stream>>>(xyz, flag);
    init_s_kernel<<<(N * 128 + 255) / 256, 256, 0, stream>>>(cg_s, s_acc, s_hi, s_lo, N * 128, flag);
    hipMemsetAsync(vA, 0, (size_t)N * 384 * sizeof(float), stream);
    hipMemsetAsync(deg, 0, (size_t)N * sizeof(int), stream);
    geom_kernel<<<(E + 255) / 256, 256, 0, stream>>>(xyz, nbr, unitv, rbfp, env, E, flag);
    deg_kernel<<<(E + 255) / 256, 256, 0, stream>>>(nbr, env, deg, E);
    scan_kernel<<<1, 256, 0, stream>>>(deg, rowptr, N);
    scatter_kernel<<<(E + 255) / 256, 256, 0, stream>>>(nbr, env, deg, elist, E);
    prep_frags_kernel<<<(3 * 4 * 8 * 64 + 3 * 4 * 24 * 64 + 255) / 256, 256, 0, stream>>>(
        W1, W2, B1hi, B1lo, B2hi, B2lo, flag);

    const int gx = (N + 63) / 64;
    const float* vbufs[4] = {vA, vB, vA, vB};
    for (int l = 0; l < 3; l++) {
        mfma_gemm<1, 0><<<dim3(gx, 2), 256, 0, stream>>>(
            s_hi, s_lo, B1hi + (size_t)l * 4 * 8 * 64 * 8, B1lo + (size_t)l * 4 * 8 * 64 * 8,
            b1, (size_t)l * 128, h_hi, h_lo, N, 128, flag);
        mfma_gemm<0, 1><<<dim3(gx, 6), 256, 0, stream>>>(
            h_hi, h_lo, B2hi + (size_t)l * 4 * 24 * 64 * 8, B2lo + (size_t)l * 4 * 24 * 64 * 8,
            b2, (size_t)l * 384, phi, (unsigned short*)nullptr, N, 384, flag);
        node_kernel<<<N, 128, 0, stream>>>(
            rowptr, elist, nbr, env, unitv, rbfp, phi,
            Wr, (size_t)l * NRBF * 384, br, (size_t)l * 384,
            vbufs[l], s_acc, s_hi, s_lo, (float*)vbufs[l + 1], N, flag);
    }
    cast_out_kernel<<<(N * 512 + 255) / 256, 256, 0, stream>>>(s_acc, vB, d_out, N, flag);
}